// Round 5
// baseline (281.787 us; speedup 1.0000x reference)
//
#include <hip/hip_runtime.h>
#include <hip/hip_bf16.h>
#include <math.h>

#define NUM_HEADS 8
#define SEQ_L 1024
#define EPS 1e-5f
#define KVBLK 64
#define LOG2E 1.44269504088896f

typedef __bf16 bf16x8 __attribute__((ext_vector_type(8)));
typedef float f32x4 __attribute__((ext_vector_type(4)));
typedef __hip_bfloat16 bf16;

#define AS1 __attribute__((address_space(1)))
#define AS3 __attribute__((address_space(3)))

__device__ __forceinline__ void gload_lds16(const void* g, void* l) {
    __builtin_amdgcn_global_load_lds((const AS1 unsigned*)g, (AS3 unsigned*)l, 16, 0, 0);
}

__device__ __forceinline__ unsigned short bfb(float x) {
    bf16 b = __float2bfloat16(x);
    return *(unsigned short*)&b;
}

// swizzle for [R][64] bf16 LDS tiles: byte ^= ((row&7)<<4)  ==  elem ^= ((row&7)<<3)
__device__ __forceinline__ int swz64(int el, int row) { return el ^ ((row & 7) << 3); }

// ------------------------------------------------------------------
__global__ __launch_bounds__(256) void f32_to_bf16_kernel(
    const float* __restrict__ in, bf16* __restrict__ out, int n)
{
    const int i = (blockIdx.x * 256 + threadIdx.x) * 4;
    if (i >= n) return;
    const float4 v = *(const float4*)&in[i];
    out[i + 0] = __float2bfloat16(v.x);
    out[i + 1] = __float2bfloat16(v.y);
    out[i + 2] = __float2bfloat16(v.z);
    out[i + 3] = __float2bfloat16(v.w);
}

// ------------------------------------------------------------------
__global__ __launch_bounds__(256) void transpose_w(
    const float* __restrict__ W, bf16* __restrict__ Wt, int K, int N)
{
    __shared__ float t[32][33];
    const int tx = threadIdx.x & 31, ty = threadIdx.x >> 5;
    const int n0 = blockIdx.x * 32, k0 = blockIdx.y * 32;
    #pragma unroll
    for (int r = 0; r < 4; ++r)
        t[ty + 8 * r][tx] = W[(size_t)(k0 + ty + 8 * r) * N + n0 + tx];
    __syncthreads();
    #pragma unroll
    for (int r = 0; r < 4; ++r)
        Wt[(size_t)(n0 + ty + 8 * r) * K + k0 + tx] = __float2bfloat16(t[tx][ty + 8 * r]);
}

// ------------------------------------------------------------------
// bf16 MFMA GEMM (m97 structure): C[M,N] = A[M,K] @ Bt[N,K]^T + bias.
// ------------------------------------------------------------------
__global__ __launch_bounds__(256) void gemm_bf16(
    const bf16* __restrict__ A, const bf16* __restrict__ Bt,
    const float* __restrict__ bias,
    float* __restrict__ C, bf16* __restrict__ Cb,
    int M, int N, int K, int relu)
{
    __shared__ __align__(16) bf16 Abuf[128 * 32];
    __shared__ __align__(16) bf16 Bbuf[128 * 32];
    const int tid = threadIdx.x;
    const int wv = tid >> 6, lane = tid & 63;
    const int row0 = blockIdx.y * 128, col0 = blockIdx.x * 128;
    const int wm = (wv >> 1) * 64, wn = (wv & 1) * 64;
    const int r0 = lane & 15, kb = lane >> 4;

    f32x4 acc[4][4] = {};
    const int arow = lane >> 2;
    const int akoff = (lane & 3) * 8;

    for (int k0 = 0; k0 < K; k0 += 32) {
        #pragma unroll
        for (int s = 0; s < 2; ++s) {
            const int c = 2 * wv + s;
            gload_lds16(&A[(size_t)(row0 + c * 16 + arow) * K + k0 + akoff], &Abuf[c * 512]);
            gload_lds16(&Bt[(size_t)(col0 + c * 16 + arow) * K + k0 + akoff], &Bbuf[c * 512]);
        }
        __syncthreads();

        bf16x8 a[4], b[4];
        #pragma unroll
        for (int i = 0; i < 4; ++i)
            a[i] = *(const bf16x8*)&Abuf[(wm + i * 16 + r0) * 32 + kb * 8];
        #pragma unroll
        for (int j = 0; j < 4; ++j)
            b[j] = *(const bf16x8*)&Bbuf[(wn + j * 16 + r0) * 32 + kb * 8];
        #pragma unroll
        for (int i = 0; i < 4; ++i)
            #pragma unroll
            for (int j = 0; j < 4; ++j)
                acc[i][j] = __builtin_amdgcn_mfma_f32_16x16x32_bf16(a[i], b[j], acc[i][j], 0, 0, 0);
        __syncthreads();
    }

    float bv[4];
    #pragma unroll
    for (int j = 0; j < 4; ++j) bv[j] = bias[col0 + wn + j * 16 + r0];

    #pragma unroll
    for (int i = 0; i < 4; ++i) {
        #pragma unroll
        for (int j = 0; j < 4; ++j) {
            const int col = col0 + wn + j * 16 + r0;
            #pragma unroll
            for (int reg = 0; reg < 4; ++reg) {
                const int row = row0 + wm + i * 16 + kb * 4 + reg;
                float v = acc[i][j][reg] + bv[j];
                if (relu) v = fmaxf(v, 0.f);
                if (C)  C[(size_t)row * N + col] = v;
                if (Cb) Cb[(size_t)row * N + col] = __float2bfloat16(v);
            }
        }
    }
}

// ------------------------------------------------------------------
// QKV GEMM with split epilogue -> Qb (scaled 0.125*log2e), Kb, Vtb.
// ------------------------------------------------------------------
__global__ __launch_bounds__(256) void gemm_qkv(
    const bf16* __restrict__ A, const bf16* __restrict__ Bt,
    const float* __restrict__ bias,
    bf16* __restrict__ Qb, bf16* __restrict__ Kb, bf16* __restrict__ Vtb,
    int M, int N, int K)
{
    __shared__ __align__(16) bf16 Abuf[128 * 32];
    __shared__ __align__(16) bf16 Bbuf[128 * 32];
    const int tid = threadIdx.x;
    const int wv = tid >> 6, lane = tid & 63;
    const int row0 = blockIdx.y * 128, col0 = blockIdx.x * 128;
    const int wm = (wv >> 1) * 64, wn = (wv & 1) * 64;
    const int r0 = lane & 15, kb = lane >> 4;

    f32x4 acc[4][4] = {};
    const int arow = lane >> 2;
    const int akoff = (lane & 3) * 8;

    for (int k0 = 0; k0 < K; k0 += 32) {
        #pragma unroll
        for (int s = 0; s < 2; ++s) {
            const int c = 2 * wv + s;
            gload_lds16(&A[(size_t)(row0 + c * 16 + arow) * K + k0 + akoff], &Abuf[c * 512]);
            gload_lds16(&Bt[(size_t)(col0 + c * 16 + arow) * K + k0 + akoff], &Bbuf[c * 512]);
        }
        __syncthreads();

        bf16x8 a[4], b[4];
        #pragma unroll
        for (int i = 0; i < 4; ++i)
            a[i] = *(const bf16x8*)&Abuf[(wm + i * 16 + r0) * 32 + kb * 8];
        #pragma unroll
        for (int j = 0; j < 4; ++j)
            b[j] = *(const bf16x8*)&Bbuf[(wn + j * 16 + r0) * 32 + kb * 8];
        #pragma unroll
        for (int i = 0; i < 4; ++i)
            #pragma unroll
            for (int j = 0; j < 4; ++j)
                acc[i][j] = __builtin_amdgcn_mfma_f32_16x16x32_bf16(a[i], b[j], acc[i][j], 0, 0, 0);
        __syncthreads();
    }

    #pragma unroll
    for (int i = 0; i < 4; ++i) {
        #pragma unroll
        for (int j = 0; j < 4; ++j) {
            const int col = col0 + wn + j * 16 + r0;     // 0..1535
            const float bv = bias[col];
            const int region = col >> 9;                  // 0=q 1=k 2=v
            const int cc = col & 511;
            const int head = cc >> 6, d = cc & 63;
            const int l0 = row0 + wm + i * 16 + kb * 4;
            const int b_ = l0 >> 10, l_ = l0 & 1023;
            if (region == 2) {
                unsigned short pk[4];
                #pragma unroll
                for (int reg = 0; reg < 4; ++reg) pk[reg] = bfb(acc[i][j][reg] + bv);
                *(ushort4*)&Vtb[((size_t)(b_ * NUM_HEADS + head) * 64 + d) * SEQ_L + l_] =
                    make_ushort4(pk[0], pk[1], pk[2], pk[3]);
            } else {
                const float s = (region == 0) ? (0.125f * LOG2E) : 1.0f;
                bf16* dst = (region == 0) ? Qb : Kb;
                #pragma unroll
                for (int reg = 0; reg < 4; ++reg) {
                    dst[((size_t)(b_ * NUM_HEADS + head) * SEQ_L + l_ + reg) * 64 + d] =
                        __float2bfloat16((acc[i][j][reg] + bv) * s);
                }
            }
        }
    }
}

// ------------------------------------------------------------------
// MFMA flash attention, raw-barrier pipelined. 4 waves / 64 q-rows.
// Single K/V LDS buffer; next-chunk loads issued during compute and
// kept in flight ACROSS barriers (raw s_barrier, no vmcnt drain).
// Softmax in log2 domain (Q pre-scaled by 0.125*log2e).
// ------------------------------------------------------------------
__global__ __launch_bounds__(256) void attn_mfma(
    const bf16* __restrict__ Qb, const bf16* __restrict__ Kb,
    const bf16* __restrict__ Vtb, const float* __restrict__ abias,
    const int* __restrict__ mask, bf16* __restrict__ out)
{
    const int bh = blockIdx.y;               // 0..63
    const int b = bh >> 3, h = bh & 7;
    const int q0 = blockIdx.x * 64;
    const int tid = threadIdx.x;
    const int wv = tid >> 6, lane = tid & 63;
    const int ql = lane & 15;
    const int hi = lane >> 4;

    __shared__ __align__(16) bf16 Ks[KVBLK * 64];
    __shared__ __align__(16) bf16 Vs[64 * KVBLK];
    __shared__ __align__(16) bf16 Ps[4][16 * 64];
    __shared__ float maskf[KVBLK];

    const int qrow = q0 + wv * 16 + ql;
    bf16x8 qf[2];
    #pragma unroll
    for (int kk = 0; kk < 2; ++kk)
        qf[kk] = *(const bf16x8*)&Qb[((size_t)bh * SEQ_L + qrow) * 64 + kk * 32 + hi * 8];

    const int sr = tid >> 3;               // 0..31
    const int sc8 = (tid & 7) * 8;

    f32x4 o[4] = {};
    float m = -1e30f, l = 0.f;
    const size_t bias_row = ((size_t)(b * NUM_HEADS + h) * SEQ_L + qrow) * SEQ_L;

    // ---- prologue: load chunk 0 into regs ----
    bf16x8 kreg[2], vreg[2];
    f32x4 breg[4];
    float mreg = 0.f;
    #pragma unroll
    for (int it = 0; it < 2; ++it) {
        const int row = sr + it * 32;
        kreg[it] = *(const bf16x8*)&Kb[((size_t)bh * SEQ_L + row) * 64 + sc8];
        vreg[it] = *(const bf16x8*)&Vtb[((size_t)bh * 64 + row) * SEQ_L + sc8];
    }
    #pragma unroll
    for (int c = 0; c < 4; ++c)
        breg[c] = *(const f32x4*)&abias[bias_row + c * 16 + hi * 4];
    if (tid < KVBLK) mreg = (mask[b * SEQ_L + tid] > 0) ? 0.f : -1e30f;

    for (int k0 = 0; k0 < SEQ_L; k0 += KVBLK) {
        // ---- barrier A: all waves done computing on previous chunk ----
        __builtin_amdgcn_sched_barrier(0);
        __builtin_amdgcn_s_barrier();
        __builtin_amdgcn_sched_barrier(0);

        // stage regs(t) -> LDS (swizzled)
        #pragma unroll
        for (int it = 0; it < 2; ++it) {
            const int row = sr + it * 32;
            *(bf16x8*)&Ks[swz64(row * 64 + sc8, row)] = kreg[it];
            *(bf16x8*)&Vs[swz64(row * 64 + sc8, row)] = vreg[it];
        }
        if (tid < KVBLK) maskf[tid] = mreg;
        asm volatile("s_waitcnt lgkmcnt(0)" ::: "memory");
        __builtin_amdgcn_sched_barrier(0);
        __builtin_amdgcn_s_barrier();          // barrier B: LDS(t) visible
        __builtin_amdgcn_sched_barrier(0);

        // p init = bias(t)*log2e + mask(t)   (consumes breg NOW)
        f32x4 p[4];
        #pragma unroll
        for (int c = 0; c < 4; ++c) {
            const f32x4 mk = *(const f32x4*)&maskf[c * 16 + hi * 4];
            #pragma unroll
            for (int reg = 0; reg < 4; ++reg)
                p[c][reg] = fmaf(breg[c][reg], LOG2E, mk[reg]);
        }

        // issue next-chunk loads into the (now free) staging regs;
        // they stay in flight across the next barrier pair (raw s_barrier)
        const int k1 = k0 + KVBLK;
        if (k1 < SEQ_L) {
            #pragma unroll
            for (int it = 0; it < 2; ++it) {
                const int row = sr + it * 32;
                kreg[it] = *(const bf16x8*)&Kb[((size_t)bh * SEQ_L + k1 + row) * 64 + sc8];
                vreg[it] = *(const bf16x8*)&Vtb[((size_t)bh * 64 + row) * SEQ_L + k1 + sc8];
            }
            #pragma unroll
            for (int c = 0; c < 4; ++c)
                breg[c] = *(const f32x4*)&abias[bias_row + k1 + c * 16 + hi * 4];
            if (tid < KVBLK) mreg = (mask[b * SEQ_L + k1 + tid] > 0) ? 0.f : -1e30f;
        }

        // S^T = K . Q^T (accumulating onto bias+mask)
        __builtin_amdgcn_s_setprio(1);
        #pragma unroll
        for (int c = 0; c < 4; ++c) {
            const int row = c * 16 + ql;
            #pragma unroll
            for (int kk = 0; kk < 2; ++kk) {
                bf16x8 kf = *(const bf16x8*)&Ks[swz64(row * 64 + kk * 32 + hi * 8, row)];
                p[c] = __builtin_amdgcn_mfma_f32_16x16x32_bf16(kf, qf[kk], p[c], 0, 0, 0);
            }
        }
        __builtin_amdgcn_s_setprio(0);

        // online softmax (log2 domain) over this chunk's 64 keys
        float mx = p[0][0];
        #pragma unroll
        for (int c = 0; c < 4; ++c)
            #pragma unroll
            for (int reg = 0; reg < 4; ++reg) mx = fmaxf(mx, p[c][reg]);
        mx = fmaxf(mx, __shfl_xor(mx, 16, 64));
        mx = fmaxf(mx, __shfl_xor(mx, 32, 64));

        const float mnew = fmaxf(m, mx);
        const float scale = __builtin_exp2f(m - mnew);
        m = mnew;
        float lsum = 0.f;
        #pragma unroll
        for (int c = 0; c < 4; ++c)
            #pragma unroll
            for (int reg = 0; reg < 4; ++reg) {
                const float pv = __builtin_exp2f(p[c][reg] - mnew);
                p[c][reg] = pv;
                lsum += pv;
            }
        lsum += __shfl_xor(lsum, 16, 64);
        lsum += __shfl_xor(lsum, 32, 64);
        l = l * scale + lsum;

        // P -> per-wave swizzled LDS (b64 packed)
        #pragma unroll
        for (int c = 0; c < 4; ++c) {
            const int el = ql * 64 + c * 16 + hi * 4;
            uint2 pk;
            pk.x = (unsigned)bfb(p[c][0]) | ((unsigned)bfb(p[c][1]) << 16);
            pk.y = (unsigned)bfb(p[c][2]) | ((unsigned)bfb(p[c][3]) << 16);
            *(uint2*)&Ps[wv][swz64(el, ql)] = pk;
        }

        // rescale O per q-row
        #pragma unroll
        for (int reg = 0; reg < 4; ++reg) {
            const float sc_q = __shfl(scale, (lane & 48) | (hi * 4 + reg), 64);
            #pragma unroll
            for (int c2 = 0; c2 < 4; ++c2) o[c2][reg] *= sc_q;
        }

        // PV: O += P @ V  (Ps is per-wave: lgkm dependency only, no barrier)
        __builtin_amdgcn_s_setprio(1);
        #pragma unroll
        for (int kk = 0; kk < 2; ++kk) {
            bf16x8 pf = *(const bf16x8*)&Ps[wv][swz64(ql * 64 + kk * 32 + hi * 8, ql)];
            #pragma unroll
            for (int c2 = 0; c2 < 4; ++c2) {
                const int vrow = c2 * 16 + ql;
                bf16x8 vf = *(const bf16x8*)&Vs[swz64(vrow * 64 + kk * 32 + hi * 8, vrow)];
                o[c2] = __builtin_amdgcn_mfma_f32_16x16x32_bf16(pf, vf, o[c2], 0, 0, 0);
            }
        }
        __builtin_amdgcn_s_setprio(0);
    }

    const float invl = (l > 0.f) ? (1.0f / l) : 0.f;
    #pragma unroll
    for (int reg = 0; reg < 4; ++reg) {
        const float inv_q = __shfl(invl, (lane & 48) | (hi * 4 + reg), 64);
        const int row = q0 + wv * 16 + hi * 4 + reg;
        #pragma unroll
        for (int c2 = 0; c2 < 4; ++c2)
            out[((size_t)(b * SEQ_L + row)) * 512 + h * 64 + c2 * 16 + ql] =
                __float2bfloat16(o[c2][reg] * inv_q);
    }
}

// ------------------------------------------------------------------
__global__ __launch_bounds__(256) void add_ln_kernel(
    const float* __restrict__ X, const float* __restrict__ Y,
    const float* __restrict__ gamma, const float* __restrict__ beta,
    float* __restrict__ out, bf16* __restrict__ outb)
{
    const int wave = threadIdx.x >> 6;
    const int lane = threadIdx.x & 63;
    const int row = blockIdx.x * 4 + wave;
    const float* xp = X + (size_t)row * 512 + lane * 8;
    const float* yp = Y + (size_t)row * 512 + lane * 8;

    float v[8];
    const float4 a0 = *(const float4*)xp;
    const float4 a1 = *(const float4*)(xp + 4);
    const float4 b0 = *(const float4*)yp;
    const float4 b1 = *(const float4*)(yp + 4);
    v[0] = a0.x + b0.x; v[1] = a0.y + b0.y; v[2] = a0.z + b0.z; v[3] = a0.w + b0.w;
    v[4] = a1.x + b1.x; v[5] = a1.y + b1.y; v[6] = a1.z + b1.z; v[7] = a1.w + b1.w;

    float s = 0.f, sq = 0.f;
    #pragma unroll
    for (int i = 0; i < 8; ++i) { s += v[i]; sq += v[i] * v[i]; }
    #pragma unroll
    for (int off = 1; off < 64; off <<= 1) {
        s += __shfl_xor(s, off, 64);
        sq += __shfl_xor(sq, off, 64);
    }
    const float mu = s * (1.f / 512.f);
    const float var = sq * (1.f / 512.f) - mu * mu;
    const float rstd = rsqrtf(var + EPS);

    const int c = lane * 8;
    const float4 g0 = *(const float4*)&gamma[c];
    const float4 g1 = *(const float4*)&gamma[c + 4];
    const float4 e0 = *(const float4*)&beta[c];
    const float4 e1 = *(const float4*)&beta[c + 4];
    float r[8];
    r[0] = (v[0] - mu) * rstd * g0.x + e0.x;
    r[1] = (v[1] - mu) * rstd * g0.y + e0.y;
    r[2] = (v[2] - mu) * rstd * g0.z + e0.z;
    r[3] = (v[3] - mu) * rstd * g0.w + e0.w;
    r[4] = (v[4] - mu) * rstd * g1.x + e1.x;
    r[5] = (v[5] - mu) * rstd * g1.y + e1.y;
    r[6] = (v[6] - mu) * rstd * g1.z + e1.z;
    r[7] = (v[7] - mu) * rstd * g1.w + e1.w;

    float* op = out + (size_t)row * 512 + c;
    *(float4*)op = make_float4(r[0], r[1], r[2], r[3]);
    *(float4*)(op + 4) = make_float4(r[4], r[5], r[6], r[7]);
    if (outb) {
        bf16* ob = outb + (size_t)row * 512 + c;
        #pragma unroll
        for (int i = 0; i < 8; ++i) ob[i] = __float2bfloat16(r[i]);
    }
}

// ------------------------------------------------------------------
extern "C" void kernel_launch(void* const* d_in, const int* in_sizes, int n_in,
                              void* d_out, int out_size, void* d_ws, size_t ws_size,
                              hipStream_t stream)
{
    const float* h    = (const float*)d_in[0];
    const float* ab   = (const float*)d_in[1];
    const int*   mask = (const int*)d_in[2];
    const float* Wqkv = (const float*)d_in[3];
    const float* bqkv = (const float*)d_in[4];
    const float* Wo   = (const float*)d_in[5];
    const float* bo   = (const float*)d_in[6];
    const float* W1   = (const float*)d_in[7];
    const float* b1   = (const float*)d_in[8];
    const float* W2   = (const float*)d_in[9];
    const float* b2   = (const float*)d_in[10];
    const float* g1   = (const float*)d_in[11];
    const float* be1  = (const float*)d_in[12];
    const float* g2   = (const float*)d_in[13];
    const float* be2  = (const float*)d_in[14];
    float* out = (float*)d_out;
    char* ws = (char*)d_ws;

    const int M = 8 * 1024;
    const size_t MB = 1024 * 1024;

    bf16*  hb   = (bf16*)(ws + 0 * MB);
    bf16*  Wtq  = (bf16*)(ws + 8 * MB);
    bf16*  Wto  = (bf16*)(ws + 10 * MB);
    bf16*  Wt1  = (bf16*)(ws + 11 * MB);
    bf16*  Wt2  = (bf16*)(ws + 13 * MB);
    bf16*  Qb   = (bf16*)(ws + 15 * MB);
    bf16*  Kb   = (bf16*)(ws + 23 * MB);
    bf16*  Vtb  = (bf16*)(ws + 31 * MB);
    bf16*  aob  = (bf16*)(ws + 39 * MB);
    float* proj = (float*)(ws + 47 * MB);
    float* h1   = (float*)(ws + 63 * MB);
    bf16*  h1b  = (bf16*)(ws + 79 * MB);
    bf16*  ffb  = (bf16*)(ws + 15 * MB);
    float* f2   = (float*)(ws + 47 * MB);

    f32_to_bf16_kernel<<<dim3(M * 512 / 1024), 256, 0, stream>>>(h, hb, M * 512);
    transpose_w<<<dim3(1536 / 32, 512 / 32), 256, 0, stream>>>(Wqkv, Wtq, 512, 1536);
    transpose_w<<<dim3(512 / 32, 512 / 32), 256, 0, stream>>>(Wo, Wto, 512, 512);
    transpose_w<<<dim3(2048 / 32, 512 / 32), 256, 0, stream>>>(W1, Wt1, 512, 2048);
    transpose_w<<<dim3(512 / 32, 2048 / 32), 256, 0, stream>>>(W2, Wt2, 2048, 512);

    gemm_qkv<<<dim3(1536 / 128, M / 128), 256, 0, stream>>>(hb, Wtq, bqkv, Qb, Kb, Vtb, M, 1536, 512);
    attn_mfma<<<dim3(SEQ_L / 64, 64), 256, 0, stream>>>(Qb, Kb, Vtb, ab, mask, aob);
    gemm_bf16<<<dim3(512 / 128, M / 128), 256, 0, stream>>>(aob, Wto, bo, proj, nullptr, M, 512, 512, 0);
    add_ln_kernel<<<dim3(M / 4), 256, 0, stream>>>(h, proj, g1, be1, h1, h1b);
    gemm_bf16<<<dim3(2048 / 128, M / 128), 256, 0, stream>>>(h1b, Wt1, b1, nullptr, ffb, M, 2048, 512, 1);
    gemm_bf16<<<dim3(512 / 128, M / 128), 256, 0, stream>>>(ffb, Wt2, b2, f2, nullptr, M, 512, 2048, 0);
    add_ln_kernel<<<dim3(M / 4), 256, 0, stream>>>(h1, f2, g2, be2, out, nullptr);
}

// Round 6
// 265.664 us; speedup vs baseline: 1.0607x; 1.0607x over previous
//
#include <hip/hip_runtime.h>
#include <hip/hip_bf16.h>
#include <math.h>

#define NUM_HEADS 8
#define SEQ_L 1024
#define EPS 1e-5f
#define KVBLK 64
#define LOG2E 1.44269504088896f

typedef __bf16 bf16x8 __attribute__((ext_vector_type(8)));
typedef float f32x4 __attribute__((ext_vector_type(4)));
typedef __hip_bfloat16 bf16;

#define AS1 __attribute__((address_space(1)))
#define AS3 __attribute__((address_space(3)))

__device__ __forceinline__ void gload_lds16(const void* g, void* l) {
    __builtin_amdgcn_global_load_lds((const AS1 unsigned*)g, (AS3 unsigned*)l, 16, 0, 0);
}

__device__ __forceinline__ unsigned short bfb(float x) {
    bf16 b = __float2bfloat16(x);
    return *(unsigned short*)&b;
}

// swizzle for [R][64] bf16 LDS tiles: byte ^= ((row&7)<<4)  ==  elem ^= ((row&7)<<3)
__device__ __forceinline__ int swz64(int el, int row) { return el ^ ((row & 7) << 3); }

// ------------------------------------------------------------------
__global__ __launch_bounds__(256) void f32_to_bf16_kernel(
    const float* __restrict__ in, bf16* __restrict__ out, int n)
{
    const int i = (blockIdx.x * 256 + threadIdx.x) * 4;
    if (i >= n) return;
    const float4 v = *(const float4*)&in[i];
    out[i + 0] = __float2bfloat16(v.x);
    out[i + 1] = __float2bfloat16(v.y);
    out[i + 2] = __float2bfloat16(v.z);
    out[i + 3] = __float2bfloat16(v.w);
}

// ------------------------------------------------------------------
__global__ __launch_bounds__(256) void transpose_w(
    const float* __restrict__ W, bf16* __restrict__ Wt, int K, int N)
{
    __shared__ float t[32][33];
    const int tx = threadIdx.x & 31, ty = threadIdx.x >> 5;
    const int n0 = blockIdx.x * 32, k0 = blockIdx.y * 32;
    #pragma unroll
    for (int r = 0; r < 4; ++r)
        t[ty + 8 * r][tx] = W[(size_t)(k0 + ty + 8 * r) * N + n0 + tx];
    __syncthreads();
    #pragma unroll
    for (int r = 0; r < 4; ++r)
        Wt[(size_t)(n0 + ty + 8 * r) * K + k0 + tx] = __float2bfloat16(t[tx][ty + 8 * r]);
}

// ------------------------------------------------------------------
// bf16 MFMA GEMM (m97 structure): C[M,N] = A[M,K] @ Bt[N,K]^T + bias.
// ------------------------------------------------------------------
__global__ __launch_bounds__(256) void gemm_bf16(
    const bf16* __restrict__ A, const bf16* __restrict__ Bt,
    const float* __restrict__ bias,
    float* __restrict__ C, bf16* __restrict__ Cb,
    int M, int N, int K, int relu)
{
    __shared__ __align__(16) bf16 Abuf[128 * 32];
    __shared__ __align__(16) bf16 Bbuf[128 * 32];
    const int tid = threadIdx.x;
    const int wv = tid >> 6, lane = tid & 63;
    const int row0 = blockIdx.y * 128, col0 = blockIdx.x * 128;
    const int wm = (wv >> 1) * 64, wn = (wv & 1) * 64;
    const int r0 = lane & 15, kb = lane >> 4;

    f32x4 acc[4][4] = {};
    const int arow = lane >> 2;
    const int akoff = (lane & 3) * 8;

    for (int k0 = 0; k0 < K; k0 += 32) {
        #pragma unroll
        for (int s = 0; s < 2; ++s) {
            const int c = 2 * wv + s;
            gload_lds16(&A[(size_t)(row0 + c * 16 + arow) * K + k0 + akoff], &Abuf[c * 512]);
            gload_lds16(&Bt[(size_t)(col0 + c * 16 + arow) * K + k0 + akoff], &Bbuf[c * 512]);
        }
        __syncthreads();

        bf16x8 a[4], b[4];
        #pragma unroll
        for (int i = 0; i < 4; ++i)
            a[i] = *(const bf16x8*)&Abuf[(wm + i * 16 + r0) * 32 + kb * 8];
        #pragma unroll
        for (int j = 0; j < 4; ++j)
            b[j] = *(const bf16x8*)&Bbuf[(wn + j * 16 + r0) * 32 + kb * 8];
        #pragma unroll
        for (int i = 0; i < 4; ++i)
            #pragma unroll
            for (int j = 0; j < 4; ++j)
                acc[i][j] = __builtin_amdgcn_mfma_f32_16x16x32_bf16(a[i], b[j], acc[i][j], 0, 0, 0);
        __syncthreads();
    }

    float bv[4];
    #pragma unroll
    for (int j = 0; j < 4; ++j) bv[j] = bias[col0 + wn + j * 16 + r0];

    #pragma unroll
    for (int i = 0; i < 4; ++i) {
        #pragma unroll
        for (int j = 0; j < 4; ++j) {
            const int col = col0 + wn + j * 16 + r0;
            #pragma unroll
            for (int reg = 0; reg < 4; ++reg) {
                const int row = row0 + wm + i * 16 + kb * 4 + reg;
                float v = acc[i][j][reg] + bv[j];
                if (relu) v = fmaxf(v, 0.f);
                if (C)  C[(size_t)row * N + col] = v;
                if (Cb) Cb[(size_t)row * N + col] = __float2bfloat16(v);
            }
        }
    }
}

// ------------------------------------------------------------------
// QKV GEMM with split epilogue -> Qb (scaled 0.125*log2e), Kb, Vtb.
// ------------------------------------------------------------------
__global__ __launch_bounds__(256) void gemm_qkv(
    const bf16* __restrict__ A, const bf16* __restrict__ Bt,
    const float* __restrict__ bias,
    bf16* __restrict__ Qb, bf16* __restrict__ Kb, bf16* __restrict__ Vtb,
    int M, int N, int K)
{
    __shared__ __align__(16) bf16 Abuf[128 * 32];
    __shared__ __align__(16) bf16 Bbuf[128 * 32];
    const int tid = threadIdx.x;
    const int wv = tid >> 6, lane = tid & 63;
    const int row0 = blockIdx.y * 128, col0 = blockIdx.x * 128;
    const int wm = (wv >> 1) * 64, wn = (wv & 1) * 64;
    const int r0 = lane & 15, kb = lane >> 4;

    f32x4 acc[4][4] = {};
    const int arow = lane >> 2;
    const int akoff = (lane & 3) * 8;

    for (int k0 = 0; k0 < K; k0 += 32) {
        #pragma unroll
        for (int s = 0; s < 2; ++s) {
            const int c = 2 * wv + s;
            gload_lds16(&A[(size_t)(row0 + c * 16 + arow) * K + k0 + akoff], &Abuf[c * 512]);
            gload_lds16(&Bt[(size_t)(col0 + c * 16 + arow) * K + k0 + akoff], &Bbuf[c * 512]);
        }
        __syncthreads();

        bf16x8 a[4], b[4];
        #pragma unroll
        for (int i = 0; i < 4; ++i)
            a[i] = *(const bf16x8*)&Abuf[(wm + i * 16 + r0) * 32 + kb * 8];
        #pragma unroll
        for (int j = 0; j < 4; ++j)
            b[j] = *(const bf16x8*)&Bbuf[(wn + j * 16 + r0) * 32 + kb * 8];
        #pragma unroll
        for (int i = 0; i < 4; ++i)
            #pragma unroll
            for (int j = 0; j < 4; ++j)
                acc[i][j] = __builtin_amdgcn_mfma_f32_16x16x32_bf16(a[i], b[j], acc[i][j], 0, 0, 0);
        __syncthreads();
    }

    #pragma unroll
    for (int i = 0; i < 4; ++i) {
        #pragma unroll
        for (int j = 0; j < 4; ++j) {
            const int col = col0 + wn + j * 16 + r0;     // 0..1535
            const float bv = bias[col];
            const int region = col >> 9;                  // 0=q 1=k 2=v
            const int cc = col & 511;
            const int head = cc >> 6, d = cc & 63;
            const int l0 = row0 + wm + i * 16 + kb * 4;
            const int b_ = l0 >> 10, l_ = l0 & 1023;
            if (region == 2) {
                unsigned short pk[4];
                #pragma unroll
                for (int reg = 0; reg < 4; ++reg) pk[reg] = bfb(acc[i][j][reg] + bv);
                *(ushort4*)&Vtb[((size_t)(b_ * NUM_HEADS + head) * 64 + d) * SEQ_L + l_] =
                    make_ushort4(pk[0], pk[1], pk[2], pk[3]);
            } else {
                const float s = (region == 0) ? (0.125f * LOG2E) : 1.0f;
                bf16* dst = (region == 0) ? Qb : Kb;
                #pragma unroll
                for (int reg = 0; reg < 4; ++reg) {
                    dst[((size_t)(b_ * NUM_HEADS + head) * SEQ_L + l_ + reg) * 64 + d] =
                        __float2bfloat16((acc[i][j][reg] + bv) * s);
                }
            }
        }
    }
}

// ------------------------------------------------------------------
// MFMA flash attention (r3 barrier structure) with COALESCED bias
// loads redistributed through wave-private swizzled LDS.
// 4 waves / 64 q-rows per block; softmax in log2 domain.
// ------------------------------------------------------------------
__global__ __launch_bounds__(256) void attn_mfma(
    const bf16* __restrict__ Qb, const bf16* __restrict__ Kb,
    const bf16* __restrict__ Vtb, const float* __restrict__ abias,
    const int* __restrict__ mask, bf16* __restrict__ out)
{
    const int bh = blockIdx.y;               // 0..63
    const int b = bh >> 3, h = bh & 7;
    const int q0 = blockIdx.x * 64;
    const int tid = threadIdx.x;
    const int wv = tid >> 6, lane = tid & 63;
    const int ql = lane & 15;
    const int hi = lane >> 4;

    __shared__ __align__(16) bf16 Ks[KVBLK * 64];
    __shared__ __align__(16) bf16 Vs[64 * KVBLK];
    __shared__ __align__(16) bf16 Ps[4][16 * 64];
    __shared__ __align__(16) float biasL[4][16 * 64];   // per-wave [qrow][key] swizzled
    __shared__ float maskf[KVBLK];

    const int qrow = q0 + wv * 16 + ql;
    bf16x8 qf[2];
    #pragma unroll
    for (int kk = 0; kk < 2; ++kk)
        qf[kk] = *(const bf16x8*)&Qb[((size_t)bh * SEQ_L + qrow) * 64 + kk * 32 + hi * 8];

    const int sr = tid >> 3;                 // K/V staging row 0..31
    const int sc8 = (tid & 7) * 8;
    const int br = lane >> 4;                // bias load: row group 0..3
    const int bc = (lane & 15) * 4;          // bias load: col

    f32x4 o[4] = {};
    float m = -1e30f, l = 0.f;
    // coalesced bias base: row block q0 + wv*16 (+ s*4 + br per instr)
    const size_t bias_base = ((size_t)(b * NUM_HEADS + h) * SEQ_L + q0 + wv * 16) * SEQ_L;

    // ---- prologue: load chunk 0 into regs (coalesced patterns) ----
    bf16x8 kreg[2], vreg[2];
    f32x4 breg[4];
    float mreg = 0.f;
    #pragma unroll
    for (int it = 0; it < 2; ++it) {
        const int row = sr + it * 32;
        kreg[it] = *(const bf16x8*)&Kb[((size_t)bh * SEQ_L + row) * 64 + sc8];
        vreg[it] = *(const bf16x8*)&Vtb[((size_t)bh * 64 + row) * SEQ_L + sc8];
    }
    #pragma unroll
    for (int s = 0; s < 4; ++s)     // rows s*4+br, cols bc..bc+3: 4 rows x 256B
        breg[s] = *(const f32x4*)&abias[bias_base + (size_t)(s * 4 + br) * SEQ_L + bc];
    if (tid < KVBLK) mreg = (mask[b * SEQ_L + tid] > 0) ? 0.f : -1e30f;

    for (int k0 = 0; k0 < SEQ_L; k0 += KVBLK) {
        __syncthreads();   // prev chunk fully consumed

        // stage K/V (swizzled) + mask
        #pragma unroll
        for (int it = 0; it < 2; ++it) {
            const int row = sr + it * 32;
            *(bf16x8*)&Ks[swz64(row * 64 + sc8, row)] = kreg[it];
            *(bf16x8*)&Vs[swz64(row * 64 + sc8, row)] = vreg[it];
        }
        if (tid < KVBLK) maskf[tid] = mreg;
        // stage bias to wave-private swizzled tile: quad' = quad ^ (row&7)
        #pragma unroll
        for (int s = 0; s < 4; ++s) {
            const int row = s * 4 + br;
            const int q = (bc >> 2) ^ (row & 7);
            *(f32x4*)&biasL[wv][row * 64 + q * 4] = breg[s];
        }
        __syncthreads();   // all LDS visible

        // issue next-chunk loads (latency hidden under this chunk's compute)
        const int k1 = k0 + KVBLK;
        if (k1 < SEQ_L) {
            #pragma unroll
            for (int it = 0; it < 2; ++it) {
                const int row = sr + it * 32;
                kreg[it] = *(const bf16x8*)&Kb[((size_t)bh * SEQ_L + k1 + row) * 64 + sc8];
                vreg[it] = *(const bf16x8*)&Vtb[((size_t)bh * 64 + row) * SEQ_L + k1 + sc8];
            }
            #pragma unroll
            for (int s = 0; s < 4; ++s)
                breg[s] = *(const f32x4*)&abias[bias_base + (size_t)(s * 4 + br) * SEQ_L + k1 + bc];
            if (tid < KVBLK) mreg = (mask[b * SEQ_L + k1 + tid] > 0) ? 0.f : -1e30f;
        }

        // p init = bias*log2e + mask (read fragment order from swizzled LDS)
        f32x4 p[4];
        #pragma unroll
        for (int c = 0; c < 4; ++c) {
            const int q = (c * 4 + hi) ^ (ql & 7);
            const f32x4 bf = *(const f32x4*)&biasL[wv][ql * 64 + q * 4];
            const f32x4 mk = *(const f32x4*)&maskf[c * 16 + hi * 4];
            #pragma unroll
            for (int reg = 0; reg < 4; ++reg)
                p[c][reg] = fmaf(bf[reg], LOG2E, mk[reg]);
        }

        // S^T = K . Q^T (accumulating onto bias+mask)
        __builtin_amdgcn_s_setprio(1);
        #pragma unroll
        for (int c = 0; c < 4; ++c) {
            const int row = c * 16 + ql;
            #pragma unroll
            for (int kk = 0; kk < 2; ++kk) {
                bf16x8 kf = *(const bf16x8*)&Ks[swz64(row * 64 + kk * 32 + hi * 8, row)];
                p[c] = __builtin_amdgcn_mfma_f32_16x16x32_bf16(kf, qf[kk], p[c], 0, 0, 0);
            }
        }
        __builtin_amdgcn_s_setprio(0);

        // online softmax (log2 domain)
        float mx = p[0][0];
        #pragma unroll
        for (int c = 0; c < 4; ++c)
            #pragma unroll
            for (int reg = 0; reg < 4; ++reg) mx = fmaxf(mx, p[c][reg]);
        mx = fmaxf(mx, __shfl_xor(mx, 16, 64));
        mx = fmaxf(mx, __shfl_xor(mx, 32, 64));

        const float mnew = fmaxf(m, mx);
        const float scale = __builtin_exp2f(m - mnew);
        m = mnew;
        float lsum = 0.f;
        #pragma unroll
        for (int c = 0; c < 4; ++c)
            #pragma unroll
            for (int reg = 0; reg < 4; ++reg) {
                const float pv = __builtin_exp2f(p[c][reg] - mnew);
                p[c][reg] = pv;
                lsum += pv;
            }
        lsum += __shfl_xor(lsum, 16, 64);
        lsum += __shfl_xor(lsum, 32, 64);
        l = l * scale + lsum;

        // P -> per-wave swizzled LDS (b64 packed)
        #pragma unroll
        for (int c = 0; c < 4; ++c) {
            const int el = ql * 64 + c * 16 + hi * 4;
            uint2 pk;
            pk.x = (unsigned)bfb(p[c][0]) | ((unsigned)bfb(p[c][1]) << 16);
            pk.y = (unsigned)bfb(p[c][2]) | ((unsigned)bfb(p[c][3]) << 16);
            *(uint2*)&Ps[wv][swz64(el, ql)] = pk;
        }

        // rescale O per q-row
        #pragma unroll
        for (int reg = 0; reg < 4; ++reg) {
            const float sc_q = __shfl(scale, (lane & 48) | (hi * 4 + reg), 64);
            #pragma unroll
            for (int c2 = 0; c2 < 4; ++c2) o[c2][reg] *= sc_q;
        }

        // PV: O += P @ V (Ps per-wave: lgkm dependency only)
        __builtin_amdgcn_s_setprio(1);
        #pragma unroll
        for (int kk = 0; kk < 2; ++kk) {
            bf16x8 pf = *(const bf16x8*)&Ps[wv][swz64(ql * 64 + kk * 32 + hi * 8, ql)];
            #pragma unroll
            for (int c2 = 0; c2 < 4; ++c2) {
                const int vrow = c2 * 16 + ql;
                bf16x8 vf = *(const bf16x8*)&Vs[swz64(vrow * 64 + kk * 32 + hi * 8, vrow)];
                o[c2] = __builtin_amdgcn_mfma_f32_16x16x32_bf16(pf, vf, o[c2], 0, 0, 0);
            }
        }
        __builtin_amdgcn_s_setprio(0);
    }

    const float invl = (l > 0.f) ? (1.0f / l) : 0.f;
    #pragma unroll
    for (int reg = 0; reg < 4; ++reg) {
        const float inv_q = __shfl(invl, (lane & 48) | (hi * 4 + reg), 64);
        const int row = q0 + wv * 16 + hi * 4 + reg;
        #pragma unroll
        for (int c2 = 0; c2 < 4; ++c2)
            out[((size_t)(b * SEQ_L + row)) * 512 + h * 64 + c2 * 16 + ql] =
                __float2bfloat16(o[c2][reg] * inv_q);
    }
}

// ------------------------------------------------------------------
// h1b = bf16(LayerNorm(X + Y))   (both X,Y fp32)
// ------------------------------------------------------------------
__global__ __launch_bounds__(256) void add_ln_to_bf16(
    const float* __restrict__ X, const float* __restrict__ Y,
    const float* __restrict__ gamma, const float* __restrict__ beta,
    bf16* __restrict__ outb)
{
    const int wave = threadIdx.x >> 6;
    const int lane = threadIdx.x & 63;
    const int row = blockIdx.x * 4 + wave;
    const float* xp = X + (size_t)row * 512 + lane * 8;
    const float* yp = Y + (size_t)row * 512 + lane * 8;

    float v[8];
    const float4 a0 = *(const float4*)xp;
    const float4 a1 = *(const float4*)(xp + 4);
    const float4 b0 = *(const float4*)yp;
    const float4 b1 = *(const float4*)(yp + 4);
    v[0] = a0.x + b0.x; v[1] = a0.y + b0.y; v[2] = a0.z + b0.z; v[3] = a0.w + b0.w;
    v[4] = a1.x + b1.x; v[5] = a1.y + b1.y; v[6] = a1.z + b1.z; v[7] = a1.w + b1.w;

    float s = 0.f, sq = 0.f;
    #pragma unroll
    for (int i = 0; i < 8; ++i) { s += v[i]; sq += v[i] * v[i]; }
    #pragma unroll
    for (int off = 1; off < 64; off <<= 1) {
        s += __shfl_xor(s, off, 64);
        sq += __shfl_xor(sq, off, 64);
    }
    const float mu = s * (1.f / 512.f);
    const float var = sq * (1.f / 512.f) - mu * mu;
    const float rstd = rsqrtf(var + EPS);

    const int c = lane * 8;
    const float4 g0 = *(const float4*)&gamma[c];
    const float4 g1 = *(const float4*)&gamma[c + 4];
    const float4 e0 = *(const float4*)&beta[c];
    const float4 e1 = *(const float4*)&beta[c + 4];
    float r[8];
    r[0] = (v[0] - mu) * rstd * g0.x + e0.x;
    r[1] = (v[1] - mu) * rstd * g0.y + e0.y;
    r[2] = (v[2] - mu) * rstd * g0.z + e0.z;
    r[3] = (v[3] - mu) * rstd * g0.w + e0.w;
    r[4] = (v[4] - mu) * rstd * g1.x + e1.x;
    r[5] = (v[5] - mu) * rstd * g1.y + e1.y;
    r[6] = (v[6] - mu) * rstd * g1.z + e1.z;
    r[7] = (v[7] - mu) * rstd * g1.w + e1.w;

    uint4 w;
    w.x = (unsigned)bfb(r[0]) | ((unsigned)bfb(r[1]) << 16);
    w.y = (unsigned)bfb(r[2]) | ((unsigned)bfb(r[3]) << 16);
    w.z = (unsigned)bfb(r[4]) | ((unsigned)bfb(r[5]) << 16);
    w.w = (unsigned)bfb(r[6]) | ((unsigned)bfb(r[7]) << 16);
    *(uint4*)&outb[(size_t)row * 512 + c] = w;
}

// ------------------------------------------------------------------
// out = fp32(LayerNorm(bf16 Xb + fp32 Y))
// ------------------------------------------------------------------
__global__ __launch_bounds__(256) void add_ln_from_bf16(
    const bf16* __restrict__ Xb, const float* __restrict__ Y,
    const float* __restrict__ gamma, const float* __restrict__ beta,
    float* __restrict__ out)
{
    const int wave = threadIdx.x >> 6;
    const int lane = threadIdx.x & 63;
    const int row = blockIdx.x * 4 + wave;
    const bf16x8 xv = *(const bf16x8*)&Xb[(size_t)row * 512 + lane * 8];
    const float* yp = Y + (size_t)row * 512 + lane * 8;

    float v[8];
    const float4 b0 = *(const float4*)yp;
    const float4 b1 = *(const float4*)(yp + 4);
    v[0] = (float)xv[0] + b0.x; v[1] = (float)xv[1] + b0.y;
    v[2] = (float)xv[2] + b0.z; v[3] = (float)xv[3] + b0.w;
    v[4] = (float)xv[4] + b1.x; v[5] = (float)xv[5] + b1.y;
    v[6] = (float)xv[6] + b1.z; v[7] = (float)xv[7] + b1.w;

    float s = 0.f, sq = 0.f;
    #pragma unroll
    for (int i = 0; i < 8; ++i) { s += v[i]; sq += v[i] * v[i]; }
    #pragma unroll
    for (int off = 1; off < 64; off <<= 1) {
        s += __shfl_xor(s, off, 64);
        sq += __shfl_xor(sq, off, 64);
    }
    const float mu = s * (1.f / 512.f);
    const float var = sq * (1.f / 512.f) - mu * mu;
    const float rstd = rsqrtf(var + EPS);

    const int c = lane * 8;
    const float4 g0 = *(const float4*)&gamma[c];
    const float4 g1 = *(const float4*)&gamma[c + 4];
    const float4 e0 = *(const float4*)&beta[c];
    const float4 e1 = *(const float4*)&beta[c + 4];
    float4 r0, r1;
    r0.x = (v[0] - mu) * rstd * g0.x + e0.x;
    r0.y = (v[1] - mu) * rstd * g0.y + e0.y;
    r0.z = (v[2] - mu) * rstd * g0.z + e0.z;
    r0.w = (v[3] - mu) * rstd * g0.w + e0.w;
    r1.x = (v[4] - mu) * rstd * g1.x + e1.x;
    r1.y = (v[5] - mu) * rstd * g1.y + e1.y;
    r1.z = (v[6] - mu) * rstd * g1.z + e1.z;
    r1.w = (v[7] - mu) * rstd * g1.w + e1.w;
    float* op = out + (size_t)row * 512 + c;
    *(float4*)op = r0;
    *(float4*)(op + 4) = r1;
}

// ------------------------------------------------------------------
extern "C" void kernel_launch(void* const* d_in, const int* in_sizes, int n_in,
                              void* d_out, int out_size, void* d_ws, size_t ws_size,
                              hipStream_t stream)
{
    const float* h    = (const float*)d_in[0];
    const float* ab   = (const float*)d_in[1];
    const int*   mask = (const int*)d_in[2];
    const float* Wqkv = (const float*)d_in[3];
    const float* bqkv = (const float*)d_in[4];
    const float* Wo   = (const float*)d_in[5];
    const float* bo   = (const float*)d_in[6];
    const float* W1   = (const float*)d_in[7];
    const float* b1   = (const float*)d_in[8];
    const float* W2   = (const float*)d_in[9];
    const float* b2   = (const float*)d_in[10];
    const float* g1   = (const float*)d_in[11];
    const float* be1  = (const float*)d_in[12];
    const float* g2   = (const float*)d_in[13];
    const float* be2  = (const float*)d_in[14];
    float* out = (float*)d_out;
    char* ws = (char*)d_ws;

    const int M = 8 * 1024;
    const size_t MB = 1024 * 1024;

    bf16*  hb   = (bf16*)(ws + 0 * MB);     // 8MB (dead after QKV)
    bf16*  Wtq  = (bf16*)(ws + 8 * MB);     // 1.5MB
    bf16*  Wto  = (bf16*)(ws + 10 * MB);    // 0.5MB
    bf16*  Wt1  = (bf16*)(ws + 11 * MB);    // 2MB
    bf16*  Wt2  = (bf16*)(ws + 13 * MB);    // 2MB
    bf16*  Qb   = (bf16*)(ws + 15 * MB);    // 8MB (dead after attn)
    bf16*  Kb   = (bf16*)(ws + 23 * MB);    // 8MB (dead after attn)
    bf16*  Vtb  = (bf16*)(ws + 31 * MB);    // 8MB (dead after attn)
    bf16*  aob  = (bf16*)(ws + 39 * MB);    // 8MB (dead after proj)
    float* proj = (float*)(ws + 47 * MB);   // 16MB (dead after LN1)
    bf16*  h1b  = (bf16*)(ws + 63 * MB);    // 8MB (live till LN2)
    bf16*  ffb  = (bf16*)(ws + 71 * MB);    // 32MB
    float* f2   = (float*)(ws + 15 * MB);   // 16MB (reuses Qb/Kb region)

    f32_to_bf16_kernel<<<dim3(M * 512 / 1024), 256, 0, stream>>>(h, hb, M * 512);
    transpose_w<<<dim3(1536 / 32, 512 / 32), 256, 0, stream>>>(Wqkv, Wtq, 512, 1536);
    transpose_w<<<dim3(512 / 32, 512 / 32), 256, 0, stream>>>(Wo, Wto, 512, 512);
    transpose_w<<<dim3(2048 / 32, 512 / 32), 256, 0, stream>>>(W1, Wt1, 512, 2048);
    transpose_w<<<dim3(512 / 32, 2048 / 32), 256, 0, stream>>>(W2, Wt2, 2048, 512);

    gemm_qkv<<<dim3(1536 / 128, M / 128), 256, 0, stream>>>(hb, Wtq, bqkv, Qb, Kb, Vtb, M, 1536, 512);
    attn_mfma<<<dim3(SEQ_L / 64, 64), 256, 0, stream>>>(Qb, Kb, Vtb, ab, mask, aob);
    gemm_bf16<<<dim3(512 / 128, M / 128), 256, 0, stream>>>(aob, Wto, bo, proj, nullptr, M, 512, 512, 0);
    add_ln_to_bf16<<<dim3(M / 4), 256, 0, stream>>>(h, proj, g1, be1, h1b);
    gemm_bf16<<<dim3(2048 / 128, M / 128), 256, 0, stream>>>(h1b, Wt1, b1, nullptr, ffb, M, 2048, 512, 1);
    gemm_bf16<<<dim3(512 / 128, M / 128), 256, 0, stream>>>(ffb, Wt2, b2, f2, nullptr, M, 512, 2048, 0);
    add_ln_from_bf16<<<dim3(M / 4), 256, 0, stream>>>(h1b, f2, g2, be2, out);
}